// Round 9
// baseline (130.014 us; speedup 1.0000x reference)
//
#include <hip/hip_runtime.h>
#include <math.h>

#define H 24
#define B0 4096       // dst nodes per bucket (LDS bins)
#define B0_SHIFT 12
#define MAXNB 64      // >= NB = ceil(N/B0) = 49
#define NBPAD 65      // replica stride (bank-spread)
#define REP 4         // phase-1 count replicas
#define P 8           // partial copies per bucket
#define CAP 70000     // bucket capacity (mean 65306, +18 sigma)
#define K1_EPB 4096   // edges per scatter block
#define EPT (K1_EPB / 256)

__device__ __forceinline__ float sigmoidf_(float v) {
    return 1.0f / (1.0f + __expf(-v));
}
// tanh via exp2-backed __expf: exact at saturation, ~1e-6 rel error
__device__ __forceinline__ float tanhf_(float v) {
    return 1.0f - 2.0f / (__expf(2.0f * v) + 1.0f);
}

// ---- K0: g[k] = sum_j lin_w[j]*gcn_w[j,k]; cb; cursors[i] = i*CAP ----
__global__ void init_kernel(unsigned* __restrict__ cursors,
                            const float* __restrict__ gcn_w,
                            const float* __restrict__ gcn_b,
                            const float* __restrict__ lin_w,
                            const float* __restrict__ lin_b,
                            float* __restrict__ g, float* __restrict__ cb, int NB) {
    int t = threadIdx.x;
    if (t < H) {
        float acc = 0.0f;
        for (int j = 0; j < H; j++) acc = fmaf(lin_w[j], gcn_w[j * H + t], acc);
        g[t] = acc;
    }
    if (t == 32) {
        float c = lin_b[0];
        for (int j = 0; j < H; j++) c = fmaf(gcn_b[j], lin_w[j], c);
        *cb = c;
    }
    if (t < MAXNB) cursors[t] = (unsigned)t * CAP;
}

// ---- fused: scatter blocks (memory/LDS-atomic-bound) + node blocks (VALU-bound)
// interleaved 1:2 so each CU co-hosts both kinds and fills both pipes.
__global__ __launch_bounds__(256) void fused_kernel(
    // scatter args
    const int* __restrict__ src, const int* __restrict__ dst,
    unsigned* __restrict__ cursors, unsigned* __restrict__ pedge, int E, int NB, int nscat,
    // node args
    const float* __restrict__ x, const float* __restrict__ h0, const float* __restrict__ c0,
    const float* __restrict__ w_ih, const float* __restrict__ w_hh,
    const float* __restrict__ b_ih, const float* __restrict__ b_hh,
    const float* __restrict__ g,
    float* __restrict__ out_h, float* __restrict__ out_c,
    float* __restrict__ y, int N, int nnode)
{
    __shared__ union {
        struct { unsigned cnt[REP * NBPAD]; unsigned rbase[MAXNB]; unsigned c3[MAXNB]; } s;
        struct { float ws[96 * 24]; float swih[96]; float sbs[96]; float sg[24]; } n;
    } u;

    int bid = blockIdx.x;
    int r = bid % 3, third = bid / 3;

    if (r == 0 && third < nscat) {
        // ================= scatter path =================
        int start = third * K1_EPB;
        int end   = start + K1_EPB; if (end > E) end = E;
        int rep = threadIdx.x & (REP - 1);

        for (int i = threadIdx.x; i < REP * NBPAD; i += 256) u.s.cnt[i] = 0;
        __syncthreads();

        // phase 1: count (register-cache dst), non-returning LDS atomics
        unsigned dreg[EPT];
        #pragma unroll
        for (int q = 0; q < EPT; q++) {
            int e = start + q * 256 + threadIdx.x;
            if (e < end) {
                unsigned d = (unsigned)dst[e];
                dreg[q] = d;
                atomicAdd(&u.s.cnt[rep * NBPAD + (d >> B0_SHIFT)], 1u);
            }
        }
        __syncthreads();

        // phase 2: merge replicas, one global reservation per touched bucket
        for (int i = threadIdx.x; i < NB; i += 256) {
            unsigned tot = u.s.cnt[i] + u.s.cnt[NBPAD + i]
                         + u.s.cnt[2 * NBPAD + i] + u.s.cnt[3 * NBPAD + i];
            u.s.rbase[i] = tot ? atomicAdd(&cursors[i], tot) : 0u;
            u.s.c3[i] = 0;
        }
        __syncthreads();

        // phase 3: scatter; single cursor per bucket keeps runs contiguous
        #pragma unroll
        for (int q = 0; q < EPT; q++) {
            int e = start + q * 256 + threadIdx.x;
            if (e < end) {
                unsigned d = dreg[q];
                unsigned b = d >> B0_SHIFT;
                unsigned slot = atomicAdd(&u.s.c3[b], 1u);
                unsigned idx  = u.s.rbase[b] + slot;
                if (idx < (b + 1u) * CAP)   // overflow guard (never fires here)
                    pedge[idx] = ((unsigned)src[e] << B0_SHIFT) | (d & (B0 - 1));
            }
        }
        return;
    }

    // ================= node path =================
    int sb = (r == 0) ? third : third + 1;
    if (sb > nscat) sb = nscat;
    int nid = bid - sb;
    if (nid >= nnode) return;

    #pragma unroll 3
    for (int i = threadIdx.x; i < 96 * 24; i += 256) u.n.ws[i] = w_hh[i];
    if (threadIdx.x < 96) {
        u.n.swih[threadIdx.x] = w_ih[threadIdx.x];
        u.n.sbs[threadIdx.x]  = b_ih[threadIdx.x] + b_hh[threadIdx.x];
    } else if (threadIdx.x >= 128 && threadIdx.x < 152) {
        u.n.sg[threadIdx.x - 128] = g[threadIdx.x - 128];
    }
    __syncthreads();

    int tid = nid * 256 + threadIdx.x;
    int pr  = tid >> 2;
    int n0  = pr * 2;
    if (n0 >= N) return;
    int n1  = n0 + 1;                 // N even for this problem
    int t   = tid & 3;
    int k0  = 6 * t;

    float hp0[H], hp1[H];
    {
        const float4* a4 = (const float4*)(h0 + (size_t)n0 * H);
        const float4* b4 = (const float4*)(h0 + (size_t)n1 * H);
        #pragma unroll
        for (int q = 0; q < 6; q++) {
            float4 va = a4[q], vb = b4[q];
            hp0[4*q+0] = va.x; hp0[4*q+1] = va.y; hp0[4*q+2] = va.z; hp0[4*q+3] = va.w;
            hp1[4*q+0] = vb.x; hp1[4*q+1] = vb.y; hp1[4*q+2] = vb.z; hp1[4*q+3] = vb.w;
        }
    }
    float cp0[6], cp1[6];
    {
        const float2* a2 = (const float2*)(c0 + (size_t)n0 * H + k0);
        const float2* b2 = (const float2*)(c0 + (size_t)n1 * H + k0);
        #pragma unroll
        for (int q = 0; q < 3; q++) {
            float2 va = a2[q], vb = b2[q];
            cp0[2*q] = va.x; cp0[2*q+1] = va.y;
            cp1[2*q] = vb.x; cp1[2*q+1] = vb.y;
        }
    }
    float xv0 = x[n0], xv1 = x[n1];
    float yv0 = 0.0f, yv1 = 0.0f;

    #pragma unroll
    for (int i = 0; i < 6; i++) {
        int k = k0 + i;
        float bi = u.n.sbs[k], bf = u.n.sbs[k + 24];
        float bg = u.n.sbs[k + 48], bo = u.n.sbs[k + 72];
        float wik = u.n.swih[k], wfk = u.n.swih[k + 24];
        float wgk = u.n.swih[k + 48], wok = u.n.swih[k + 72];
        float gi0 = fmaf(xv0, wik, bi), gi1 = fmaf(xv1, wik, bi);
        float gf0 = fmaf(xv0, wfk, bf), gf1 = fmaf(xv1, wfk, bf);
        float gg0 = fmaf(xv0, wgk, bg), gg1 = fmaf(xv1, wgk, bg);
        float go0 = fmaf(xv0, wok, bo), go1 = fmaf(xv1, wok, bo);
        const float* w0 = u.n.ws + k * 24;
        #pragma unroll
        for (int c = 0; c < 6; c++) {
            float4 wi = *(const float4*)(w0 + 4*c);
            float4 wf = *(const float4*)(w0 + 576  + 4*c);
            float4 wg = *(const float4*)(w0 + 1152 + 4*c);
            float4 wo = *(const float4*)(w0 + 1728 + 4*c);
            float a0 = hp0[4*c+0], a1 = hp0[4*c+1], a2 = hp0[4*c+2], a3 = hp0[4*c+3];
            float d0 = hp1[4*c+0], d1 = hp1[4*c+1], d2 = hp1[4*c+2], d3 = hp1[4*c+3];
            gi0 = fmaf(a0, wi.x, gi0); gi0 = fmaf(a1, wi.y, gi0);
            gi0 = fmaf(a2, wi.z, gi0); gi0 = fmaf(a3, wi.w, gi0);
            gi1 = fmaf(d0, wi.x, gi1); gi1 = fmaf(d1, wi.y, gi1);
            gi1 = fmaf(d2, wi.z, gi1); gi1 = fmaf(d3, wi.w, gi1);
            gf0 = fmaf(a0, wf.x, gf0); gf0 = fmaf(a1, wf.y, gf0);
            gf0 = fmaf(a2, wf.z, gf0); gf0 = fmaf(a3, wf.w, gf0);
            gf1 = fmaf(d0, wf.x, gf1); gf1 = fmaf(d1, wf.y, gf1);
            gf1 = fmaf(d2, wf.z, gf1); gf1 = fmaf(d3, wf.w, gf1);
            gg0 = fmaf(a0, wg.x, gg0); gg0 = fmaf(a1, wg.y, gg0);
            gg0 = fmaf(a2, wg.z, gg0); gg0 = fmaf(a3, wg.w, gg0);
            gg1 = fmaf(d0, wg.x, gg1); gg1 = fmaf(d1, wg.y, gg1);
            gg1 = fmaf(d2, wg.z, gg1); gg1 = fmaf(d3, wg.w, gg1);
            go0 = fmaf(a0, wo.x, go0); go0 = fmaf(a1, wo.y, go0);
            go0 = fmaf(a2, wo.z, go0); go0 = fmaf(a3, wo.w, go0);
            go1 = fmaf(d0, wo.x, go1); go1 = fmaf(d1, wo.y, go1);
            go1 = fmaf(d2, wo.z, go1); go1 = fmaf(d3, wo.w, go1);
        }
        gi0 = sigmoidf_(gi0); gf0 = sigmoidf_(gf0); go0 = sigmoidf_(go0); gg0 = tanhf_(gg0);
        gi1 = sigmoidf_(gi1); gf1 = sigmoidf_(gf1); go1 = sigmoidf_(go1); gg1 = tanhf_(gg1);
        float c_0 = fmaf(gf0, cp0[i], gi0 * gg0);
        float c_1 = fmaf(gf1, cp1[i], gi1 * gg1);
        float h_0 = go0 * tanhf_(c_0);
        float h_1 = go1 * tanhf_(c_1);
        out_c[(size_t)n0 * H + k] = c_0;
        out_c[(size_t)n1 * H + k] = c_1;
        out_h[(size_t)n0 * H + k] = h_0;
        out_h[(size_t)n1 * H + k] = h_1;
        float gk = u.n.sg[k];
        yv0 = fmaf(h_0, gk, yv0);
        yv1 = fmaf(h_1, gk, yv1);
    }
    // quad reduce both nodes' y
    yv0 += __shfl_xor(yv0, 1); yv0 += __shfl_xor(yv0, 2);
    yv1 += __shfl_xor(yv1, 1); yv1 += __shfl_xor(yv1, 2);
    if (t == 0) y[n0] = yv0;
    if (t == 1) y[n1] = yv1;
}

// ---- K2: per-bucket LDS degree histogram -> P u16 partial copies ----
__global__ __launch_bounds__(256) void deghist_kernel(
    const unsigned* __restrict__ pedge, const unsigned* __restrict__ cursors,
    unsigned short* __restrict__ degp, int NB, int NPAD)
{
    __shared__ unsigned h[B0];
    int b = blockIdx.x % NB, p = blockIdx.x / NB;
    for (int i = threadIdx.x; i < B0; i += 256) h[i] = 0;
    __syncthreads();
    unsigned base = (unsigned)b * CAP;
    unsigned sz = cursors[b] - base; if (sz > CAP) sz = CAP;
    unsigned chunk = (sz + P - 1) / P;
    unsigned s0 = p * chunk;
    unsigned s1 = s0 + chunk; if (s1 > sz) s1 = sz;
    for (unsigned i = s0 + threadIdx.x; i < s1; i += 256)
        atomicAdd(&h[pedge[base + i] & (B0 - 1)], 1u);
    __syncthreads();
    unsigned short* out = degp + (size_t)p * NPAD + (size_t)b * B0;
    for (int i = threadIdx.x; i < B0; i += 256) out[i] = (unsigned short)h[i];
}

// ---- z: dinv from deg partials; z = dinv * y ----
__global__ __launch_bounds__(256) void z_kernel(
    const float* __restrict__ y, const unsigned short* __restrict__ degp, int NPAD,
    float* __restrict__ dinv, float* __restrict__ z, int N)
{
    int n = blockIdx.x * 256 + threadIdx.x;
    if (n >= N) return;
    unsigned dg = 0;
    #pragma unroll
    for (int p = 0; p < P; p++) dg += degp[(size_t)p * NPAD + n];
    float di = rsqrtf((float)dg + 1.0f);
    dinv[n] = di;
    z[n] = di * y[n];
}

// ---- K5: per-bucket LDS f32 accumulation of z[src] ----
__global__ __launch_bounds__(256) void acchist_kernel(
    const unsigned* __restrict__ pedge, const unsigned* __restrict__ cursors,
    const float* __restrict__ z, float* __restrict__ accp, int NB, int NPAD)
{
    __shared__ float h[B0];
    int b = blockIdx.x % NB, p = blockIdx.x / NB;
    for (int i = threadIdx.x; i < B0; i += 256) h[i] = 0.0f;
    __syncthreads();
    unsigned base = (unsigned)b * CAP;
    unsigned sz = cursors[b] - base; if (sz > CAP) sz = CAP;
    unsigned chunk = (sz + P - 1) / P;
    unsigned s0 = p * chunk;
    unsigned s1 = s0 + chunk; if (s1 > sz) s1 = sz;
    for (unsigned i = s0 + threadIdx.x; i < s1; i += 256) {
        unsigned v = pedge[base + i];
        atomicAdd(&h[v & (B0 - 1)], z[v >> B0_SHIFT]);
    }
    __syncthreads();
    float* out = accp + (size_t)p * NPAD + (size_t)b * B0;
    for (int i = threadIdx.x; i < B0; i += 256) out[i] = h[i];
}

// ---- final: sum acc partials, apply norm + bias + gate ----
__global__ __launch_bounds__(256) void final_kernel(
    const float* __restrict__ x, const float* __restrict__ accp, int NPAD,
    const float* __restrict__ y, const float* __restrict__ dinv,
    const float* __restrict__ cb, float* __restrict__ out, int N)
{
    int n = blockIdx.x * blockDim.x + threadIdx.x;
    if (n >= N) return;
    float a = 0.0f;
    #pragma unroll
    for (int p = 0; p < P; p++) a += accp[(size_t)p * NPAD + n];
    float di = dinv[n];
    float s  = di * a + di * di * y[n] + cb[0];
    out[n] = x[n] * s;
}

extern "C" void kernel_launch(void* const* d_in, const int* in_sizes, int n_in,
                              void* d_out, int out_size, void* d_ws, size_t ws_size,
                              hipStream_t stream) {
    const float* x     = (const float*)d_in[0];
    const float* h0    = (const float*)d_in[1];
    const float* c0    = (const float*)d_in[2];
    const int*   ei    = (const int*)d_in[3];
    const float* w_ih  = (const float*)d_in[4];
    const float* w_hh  = (const float*)d_in[5];
    const float* b_ih  = (const float*)d_in[6];
    const float* b_hh  = (const float*)d_in[7];
    const float* gcn_w = (const float*)d_in[8];
    const float* gcn_b = (const float*)d_in[9];
    const float* lin_w = (const float*)d_in[10];
    const float* lin_b = (const float*)d_in[11];

    const int N = in_sizes[0];
    const int E = in_sizes[3] / 2;
    const int* src = ei;
    const int* dst = ei + E;

    const int NB   = (N + B0 - 1) / B0;   // 49
    const int NPAD = NB * B0;             // 200704

    float* out_gate = (float*)d_out;
    float* out_h    = out_gate + N;
    float* out_c    = out_h + (size_t)N * H;

    // workspace layout (~26 MB)
    char* w = (char*)d_ws;
    unsigned*       pedge   = (unsigned*)w;       w += (size_t)NB * CAP * 4;   // 13.7 MB
    unsigned short* degp    = (unsigned short*)w; w += (size_t)P * NPAD * 2;   // 3.2 MB
    float*          accp    = (float*)w;          w += (size_t)P * NPAD * 4;   // 6.4 MB
    float*          y       = (float*)w;          w += (size_t)N * 4;
    float*          zv      = (float*)w;          w += (size_t)N * 4;
    float*          dinv    = (float*)w;          w += (size_t)N * 4;
    float*          g       = (float*)w;          w += H * 4;
    float*          cb      = (float*)w;          w += 4;
    unsigned*       cursors = (unsigned*)w;       w += MAXNB * 4;

    const int NSCAT = (E + K1_EPB - 1) / K1_EPB;            // 782
    const int NNODE = ((N / 2) * 4 + 255) / 256;            // 1563
    int total = NSCAT + NNODE;
    if (NNODE <= 2 * NSCAT) total = 3 * NSCAT;              // keep %3 interleave valid

    init_kernel  <<<1, 64, 0, stream>>>(cursors, gcn_w, gcn_b, lin_w, lin_b, g, cb, NB);
    fused_kernel <<<total, 256, 0, stream>>>(src, dst, cursors, pedge, E, NB, NSCAT,
                                             x, h0, c0, w_ih, w_hh, b_ih, b_hh, g,
                                             out_h, out_c, y, N, NNODE);
    deghist_kernel<<<NB * P, 256, 0, stream>>>(pedge, cursors, degp, NB, NPAD);
    z_kernel      <<<(N + 255) / 256, 256, 0, stream>>>(y, degp, NPAD, dinv, zv, N);
    acchist_kernel<<<NB * P, 256, 0, stream>>>(pedge, cursors, zv, accp, NB, NPAD);
    final_kernel  <<<(N + 255) / 256, 256, 0, stream>>>(x, accp, NPAD, y, dinv, cb,
                                                        out_gate, N);
}